// Round 1
// baseline (283.994 us; speedup 1.0000x reference)
//
#include <hip/hip_runtime.h>
#include <hip/hip_bf16.h>
#include <stdint.h>

// Problem constants
#define B_ 4
#define C_ 64
#define T_ 80
#define H_ 36
#define W_ 64
#define N_ 128
#define NT_ 10
#define S_ (H_*W_)        // 2304 = K of the GEMM
#define M_ (B_*C_*T_)     // 20480 = rows of the GEMM
#define K_ S_
#define TOUT (T_-NT_+1)   // 71

#define BM 64             // = C_: one block owns all channels of one (b,t)
#define BK 64
#define KSPLIT 4
#define KCH (K_ / KSPLIT) // 576
#define NIT (KCH / BK)    // 9 iters

using float4v = __attribute__((ext_vector_type(4))) float;
using short8v = __attribute__((ext_vector_type(8))) short;

// round-to-nearest-even fp32 -> bf16 bits
__device__ __forceinline__ unsigned short f2bf(float f) {
  unsigned int u = __float_as_uint(f);
  u += 0x7fffu + ((u >> 16) & 1u);
  return (unsigned short)(u >> 16);
}

__device__ __forceinline__ unsigned int pkbf(float a, float b) {
  union { __hip_bfloat162 h2; unsigned int u; } cv;
  cv.h2 = __float22bfloat162_rn(make_float2(a, b));
  return cv.u;
}

// async global->LDS, 16B per lane (lds dest = wave-uniform base + lane*16)
__device__ __forceinline__ void glds16(const void* g, void* l) {
  __builtin_amdgcn_global_load_lds(
      (const __attribute__((address_space(1))) unsigned int*)g,
      (__attribute__((address_space(3))) unsigned int*)l, 16, 0, 0);
}

// ---------------------------------------------------------------------------
// K1: Gaussian soft-pool weights, normalized, written fragment-packed bf16:
//     Bp[((s>>3)*N + n)*8 + (s&7)]  i.e. [K/8][N][8]
// Also zero-inits R (k2 accumulates into it with atomics).
// ---------------------------------------------------------------------------
__global__ __launch_bounds__(256) void k1_ws(const float* __restrict__ wx,
                                             const float* __restrict__ wy,
                                             const float* __restrict__ wsigx,
                                             const float* __restrict__ wsigy,
                                             unsigned short* __restrict__ Bp,
                                             float* __restrict__ R) {
  const int n = blockIdx.x;
  const int tid = threadIdx.x;

  // zero R: 40960 floats over 128 blocks x 256 threads
  {
    const int g = n * 256 + tid;           // 0..32767
    R[g] = 0.f;
    if (g < B_ * T_ * N_ - 32768) R[g + 32768] = 0.f;
  }

  const float cx = wx[n], cy = wy[n];
  const float rx = fmaxf(wsigx[n], 0.f);
  const float ry = fmaxf(wsigy[n], 0.f);
  const float i2sx = 0.5f / (0.1f + rx * rx);
  const float i2sy = 0.5f / (0.1f + ry * ry);

  float ev[9];   // 2304 = 9*256, each thread owns s = tid + i*256
  float part = 0.f;
#pragma unroll
  for (int i = 0; i < 9; ++i) {
    const int s = tid + i * 256;
    const int h = s >> 6, w = s & 63;
    const float dx = (w - 31.5f) * (1.f / 64.f) - cx;  // (w - W/2 + .5)/W
    const float dy = (h - 17.5f) * (1.f / 36.f) - cy;  // (h - H/2 + .5)/H
    const float e = __expf(-(dx * dx * i2sx + dy * dy * i2sy));
    ev[i] = e;
    part += e;
  }
#pragma unroll
  for (int off = 32; off > 0; off >>= 1) part += __shfl_down(part, off);
  __shared__ float red[4];
  if ((tid & 63) == 0) red[tid >> 6] = part;
  __syncthreads();
  const float inv = 1.f / (0.1f + red[0] + red[1] + red[2] + red[3]);
#pragma unroll
  for (int i = 0; i < 9; ++i) {
    const int s = tid + i * 256;
    Bp[((s >> 3) * N_ + n) * 8 + (s & 7)] = f2bf(ev[i] * inv);
  }
}

// ---------------------------------------------------------------------------
// K2 (fused): for block (bt, split):
//   Z[c, n] = sum_{k in split} x[(b*C+c)*T+t, k] * ws[k, n]   (c = 0..63)
//   R[bt, n] += sum_c wc[c,n] * Z[c,n]      (atomicAdd of k-split partial)
// BM=64 x BN=128 x BK=64, 256 threads = 4 waves.
// Wave decomposition is 2M x 2N: wave wv owns rows (wv&1)*32..+31 and
// cols (wv>>1)*64..+63.  vs the previous 4-way N-split this HALVES the
// per-wave LDS read traffic (each wave reads half the A tile instead of
// all of it: 32 KB not 64 KB ds_read per block-iter) and halves the
// per-wave fp32->bf16 pack work.  B-fragment (L2-resident Bp) traffic
// doubles, which the L2 absorbs.  A path unchanged:
// fp32 LDS double-buffered via global_load_lds, XOR-swizzled 16B chunks:
//    chunk(r,c4) at r*16 + (c4 ^ (r&15)).
// ---------------------------------------------------------------------------
__global__ __launch_bounds__(256, 4) void k2_fused(const float* __restrict__ A,
                                                   const unsigned short* __restrict__ Bp,
                                                   const float* __restrict__ wc,
                                                   float* __restrict__ R) {
  __shared__ float4v As[2][BM * 16];   // 2 x 16 KB
  const int tid = threadIdx.x;
  const int lane = tid & 63;
  const int wv = tid >> 6;
  const int m15 = lane & 15;
  const int q = lane >> 4;
  const int rbase = (wv & 1) * 32;     // wave's 32-row half
  const int cbase = (wv >> 1) * 64;    // wave's 64-col half
  const int bt = blockIdx.x;           // b*T + t
  const int b = bt / T_;
  const int t = bt - b * T_;
  const int split = blockIdx.y;
  const int kStart = split * KCH;

  // A staging: 1024 chunks/tile, 4 per thread; row r <-> channel c=r
  const float* ga[4];
  int lam_[4];
#pragma unroll
  for (int i = 0; i < 4; ++i) {
    const int lam = i * 256 + tid;
    const int r = lam >> 4;
    const int c4 = (lam & 15) ^ (r & 15);
    ga[i] = A + (size_t)((b * C_ + r) * T_ + t) * K_ + kStart + c4 * 4;
    lam_[i] = lam;
  }

  float4v acc[2][4];                   // [mt][nt]
#pragma unroll
  for (int i = 0; i < 2; ++i)
#pragma unroll
    for (int j = 0; j < 4; ++j) acc[i][j] = (float4v)(0.f);

  // prologue: stage k-tile 0 into buf 0
#pragma unroll
  for (int i = 0; i < 4; ++i) glds16(ga[i], &As[0][lam_[i]]);

  int cur = 0;
  for (int it = 0; it < NIT; ++it) {
    // B fragments for this iter: this wave's 64-col strip, both k-halves
    short8v bfr[2][4];                 // [ks][nt]
    const int kg0 = (kStart + it * BK) >> 3;
#pragma unroll
    for (int ks = 0; ks < 2; ++ks) {
      const int kg = kg0 + ks * 4 + q;
#pragma unroll
      for (int nt = 0; nt < 4; ++nt) {
        bfr[ks][nt] = *(const short8v*)(Bp + ((size_t)kg * N_ + cbase + nt * 16 + m15) * 8);
      }
    }

    __syncthreads();                   // buf[cur] ready for all waves
    if (it + 1 < NIT) {                // prefetch next tile into buf[cur^1]
#pragma unroll
      for (int i = 0; i < 4; ++i)
        glds16(ga[i] + (size_t)(it + 1) * BK, &As[cur ^ 1][lam_[i]]);
    }

#pragma unroll
    for (int ks = 0; ks < 2; ++ks) {
      const int c4a = ks * 8 + q * 2;
#pragma unroll
      for (int mt = 0; mt < 2; ++mt) {
        const int rowc = (rbase + mt * 16 + m15) * 16;
        const float4v alo = As[cur][rowc + (c4a ^ m15)];
        const float4v ahi = As[cur][rowc + ((c4a + 1) ^ m15)];
        union { short8v s8; unsigned int u[4]; } af;
        af.u[0] = pkbf(alo[0], alo[1]);
        af.u[1] = pkbf(alo[2], alo[3]);
        af.u[2] = pkbf(ahi[0], ahi[1]);
        af.u[3] = pkbf(ahi[2], ahi[3]);
#pragma unroll
        for (int nt = 0; nt < 4; ++nt) {
          acc[mt][nt] = __builtin_amdgcn_mfma_f32_16x16x32_bf16(af.s8, bfr[ks][nt], acc[mt][nt], 0, 0, 0);
        }
      }
    }
    cur ^= 1;
  }

  // Epilogue: C/D layout col = lane&15, row-in-tile = q*4 + reg.
  // Lane covers rows rbase + mt*16 + q*4 + v; butterfly over q gives the
  // wave's 32-row partial; waves sharing a col-half both atomicAdd.
#pragma unroll
  for (int nt = 0; nt < 4; ++nt) {
    const int n = cbase + nt * 16 + m15;
    float p = 0.f;
#pragma unroll
    for (int mt = 0; mt < 2; ++mt)
#pragma unroll
      for (int v = 0; v < 4; ++v)
        p += acc[mt][nt][v] * wc[(rbase + mt * 16 + q * 4 + v) * N_ + n];
    p += __shfl_xor(p, 16);
    p += __shfl_xor(p, 32);
    if (q == 0) atomicAdd(&R[(size_t)bt * N_ + n], p);
  }
}

// ---------------------------------------------------------------------------
// K4: out[b,n,tau] = sum_j R[b, tau+j, n] * wt[j,n] + wb[n]
// ---------------------------------------------------------------------------
__global__ __launch_bounds__(128) void k4_conv(const float* __restrict__ R,
                                               const float* __restrict__ wt,
                                               const float* __restrict__ wb,
                                               float* __restrict__ out) {
  const int n = threadIdx.x;
  const int tau = blockIdx.x;      // 0..70
  const int b = blockIdx.y;
  float s = wb[n];
#pragma unroll
  for (int j = 0; j < NT_; ++j) {
    s += R[(b * T_ + tau + j) * N_ + n] * wt[j * N_ + n];
  }
  out[((size_t)b * N_ + n) * TOUT + tau] = s;
}

extern "C" void kernel_launch(void* const* d_in, const int* in_sizes, int n_in,
                              void* d_out, int out_size, void* d_ws, size_t ws_size,
                              hipStream_t stream) {
  (void)in_sizes; (void)n_in; (void)out_size; (void)ws_size;
  const float* x    = (const float*)d_in[0];
  // d_in[1] = targets (unused by reference)
  const float* wc   = (const float*)d_in[2];
  const float* wx   = (const float*)d_in[3];
  const float* wy   = (const float*)d_in[4];
  const float* wsx  = (const float*)d_in[5];
  const float* wsy  = (const float*)d_in[6];
  const float* wt   = (const float*)d_in[7];
  const float* wb   = (const float*)d_in[8];
  float* out = (float*)d_out;

  char* ws = (char*)d_ws;
  unsigned short* Bp = (unsigned short*)ws;   // 2304*128*2 = 589824 B
  float* R = (float*)(ws + 589824);           // 320*128*4  = 163840 B

  k1_ws<<<N_, 256, 0, stream>>>(wx, wy, wsx, wsy, Bp, R);
  dim3 g2(B_ * T_, KSPLIT);
  k2_fused<<<g2, 256, 0, stream>>>(x, Bp, wc, R);
  dim3 g4(TOUT, B_);
  k4_conv<<<g4, 128, 0, stream>>>(R, wt, wb, out);
}

// Round 2
// 281.791 us; speedup vs baseline: 1.0078x; 1.0078x over previous
//
#include <hip/hip_runtime.h>
#include <hip/hip_bf16.h>
#include <stdint.h>

// Problem constants
#define B_ 4
#define C_ 64
#define T_ 80
#define H_ 36
#define W_ 64
#define N_ 128
#define NT_ 10
#define S_ (H_*W_)        // 2304 = K of the GEMM
#define M_ (B_*C_*T_)     // 20480 = rows of the GEMM
#define K_ S_
#define TOUT (T_-NT_+1)   // 71

#define BM 64             // = C_: one block owns all channels of one (b,t)
#define BK 64
// KSPLIT=3: grid = 320*3 = 960 blocks <= 1024 resident (4 blocks/CU at
// 32 KB LDS + launch_bounds(256,4)) -> single dispatch round, no 256-block
// tail at 1 block/CU (which KSPLIT=4's 1280-block grid suffered).
#define KSPLIT 3
#define KCH (K_ / KSPLIT) // 768
#define NIT (KCH / BK)    // 12 iters

using float4v = __attribute__((ext_vector_type(4))) float;
using short8v = __attribute__((ext_vector_type(8))) short;

// round-to-nearest-even fp32 -> bf16 bits
__device__ __forceinline__ unsigned short f2bf(float f) {
  unsigned int u = __float_as_uint(f);
  u += 0x7fffu + ((u >> 16) & 1u);
  return (unsigned short)(u >> 16);
}

__device__ __forceinline__ unsigned int pkbf(float a, float b) {
  union { __hip_bfloat162 h2; unsigned int u; } cv;
  cv.h2 = __float22bfloat162_rn(make_float2(a, b));
  return cv.u;
}

// async global->LDS, 16B per lane (lds dest = wave-uniform base + lane*16)
__device__ __forceinline__ void glds16(const void* g, void* l) {
  __builtin_amdgcn_global_load_lds(
      (const __attribute__((address_space(1))) unsigned int*)g,
      (__attribute__((address_space(3))) unsigned int*)l, 16, 0, 0);
}

// ---------------------------------------------------------------------------
// K1: Gaussian soft-pool weights, normalized, written fragment-packed bf16:
//     Bp[((s>>3)*N + n)*8 + (s&7)]  i.e. [K/8][N][8]
// Also zero-inits R (k2 accumulates into it with atomics).
// ---------------------------------------------------------------------------
__global__ __launch_bounds__(256) void k1_ws(const float* __restrict__ wx,
                                             const float* __restrict__ wy,
                                             const float* __restrict__ wsigx,
                                             const float* __restrict__ wsigy,
                                             unsigned short* __restrict__ Bp,
                                             float* __restrict__ R) {
  const int n = blockIdx.x;
  const int tid = threadIdx.x;

  // zero R: 40960 floats over 128 blocks x 256 threads
  {
    const int g = n * 256 + tid;           // 0..32767
    R[g] = 0.f;
    if (g < B_ * T_ * N_ - 32768) R[g + 32768] = 0.f;
  }

  const float cx = wx[n], cy = wy[n];
  const float rx = fmaxf(wsigx[n], 0.f);
  const float ry = fmaxf(wsigy[n], 0.f);
  const float i2sx = 0.5f / (0.1f + rx * rx);
  const float i2sy = 0.5f / (0.1f + ry * ry);

  float ev[9];   // 2304 = 9*256, each thread owns s = tid + i*256
  float part = 0.f;
#pragma unroll
  for (int i = 0; i < 9; ++i) {
    const int s = tid + i * 256;
    const int h = s >> 6, w = s & 63;
    const float dx = (w - 31.5f) * (1.f / 64.f) - cx;  // (w - W/2 + .5)/W
    const float dy = (h - 17.5f) * (1.f / 36.f) - cy;  // (h - H/2 + .5)/H
    const float e = __expf(-(dx * dx * i2sx + dy * dy * i2sy));
    ev[i] = e;
    part += e;
  }
#pragma unroll
  for (int off = 32; off > 0; off >>= 1) part += __shfl_down(part, off);
  __shared__ float red[4];
  if ((tid & 63) == 0) red[tid >> 6] = part;
  __syncthreads();
  const float inv = 1.f / (0.1f + red[0] + red[1] + red[2] + red[3]);
#pragma unroll
  for (int i = 0; i < 9; ++i) {
    const int s = tid + i * 256;
    Bp[((s >> 3) * N_ + n) * 8 + (s & 7)] = f2bf(ev[i] * inv);
  }
}

// ---------------------------------------------------------------------------
// K2 (fused): for block (bt, split):
//   Z[c, n] = sum_{k in split} x[(b*C+c)*T+t, k] * ws[k, n]   (c = 0..63)
//   R[bt, n] += sum_c wc[c,n] * Z[c,n]      (atomicAdd of k-split partial)
// BM=64 x BN=128 x BK=64, 256 threads = 4 waves.
// Wave decomposition 2M x 2N: wave wv owns rows (wv&1)*32..+31, cols
// (wv>>1)*64..+63.  HBM-bound (R1 A/B: LDS/VALU halving was neutral);
// A path: fp32 LDS double-buffered via global_load_lds, XOR-swizzled
// 16B chunks: chunk(r,c4) at r*16 + (c4 ^ (r&15)).
// ---------------------------------------------------------------------------
__global__ __launch_bounds__(256, 4) void k2_fused(const float* __restrict__ A,
                                                   const unsigned short* __restrict__ Bp,
                                                   const float* __restrict__ wc,
                                                   float* __restrict__ R) {
  __shared__ float4v As[2][BM * 16];   // 2 x 16 KB
  const int tid = threadIdx.x;
  const int lane = tid & 63;
  const int wv = tid >> 6;
  const int m15 = lane & 15;
  const int q = lane >> 4;
  const int rbase = (wv & 1) * 32;     // wave's 32-row half
  const int cbase = (wv >> 1) * 64;    // wave's 64-col half
  const int bt = blockIdx.x;           // b*T + t
  const int b = bt / T_;
  const int t = bt - b * T_;
  const int split = blockIdx.y;
  const int kStart = split * KCH;

  // A staging: 1024 chunks/tile, 4 per thread; row r <-> channel c=r
  const float* ga[4];
  int lam_[4];
#pragma unroll
  for (int i = 0; i < 4; ++i) {
    const int lam = i * 256 + tid;
    const int r = lam >> 4;
    const int c4 = (lam & 15) ^ (r & 15);
    ga[i] = A + (size_t)((b * C_ + r) * T_ + t) * K_ + kStart + c4 * 4;
    lam_[i] = lam;
  }

  float4v acc[2][4];                   // [mt][nt]
#pragma unroll
  for (int i = 0; i < 2; ++i)
#pragma unroll
    for (int j = 0; j < 4; ++j) acc[i][j] = (float4v)(0.f);

  // prologue: stage k-tile 0 into buf 0
#pragma unroll
  for (int i = 0; i < 4; ++i) glds16(ga[i], &As[0][lam_[i]]);

  int cur = 0;
  for (int it = 0; it < NIT; ++it) {
    // B fragments for this iter: this wave's 64-col strip, both k-halves
    short8v bfr[2][4];                 // [ks][nt]
    const int kg0 = (kStart + it * BK) >> 3;
#pragma unroll
    for (int ks = 0; ks < 2; ++ks) {
      const int kg = kg0 + ks * 4 + q;
#pragma unroll
      for (int nt = 0; nt < 4; ++nt) {
        bfr[ks][nt] = *(const short8v*)(Bp + ((size_t)kg * N_ + cbase + nt * 16 + m15) * 8);
      }
    }

    __syncthreads();                   // buf[cur] ready for all waves
    if (it + 1 < NIT) {                // prefetch next tile into buf[cur^1]
#pragma unroll
      for (int i = 0; i < 4; ++i)
        glds16(ga[i] + (size_t)(it + 1) * BK, &As[cur ^ 1][lam_[i]]);
    }

#pragma unroll
    for (int ks = 0; ks < 2; ++ks) {
      const int c4a = ks * 8 + q * 2;
#pragma unroll
      for (int mt = 0; mt < 2; ++mt) {
        const int rowc = (rbase + mt * 16 + m15) * 16;
        const float4v alo = As[cur][rowc + (c4a ^ m15)];
        const float4v ahi = As[cur][rowc + ((c4a + 1) ^ m15)];
        union { short8v s8; unsigned int u[4]; } af;
        af.u[0] = pkbf(alo[0], alo[1]);
        af.u[1] = pkbf(alo[2], alo[3]);
        af.u[2] = pkbf(ahi[0], ahi[1]);
        af.u[3] = pkbf(ahi[2], ahi[3]);
#pragma unroll
        for (int nt = 0; nt < 4; ++nt) {
          acc[mt][nt] = __builtin_amdgcn_mfma_f32_16x16x32_bf16(af.s8, bfr[ks][nt], acc[mt][nt], 0, 0, 0);
        }
      }
    }
    cur ^= 1;
  }

  // Epilogue: C/D layout col = lane&15, row-in-tile = q*4 + reg.
  // Lane covers rows rbase + mt*16 + q*4 + v; butterfly over q gives the
  // wave's 32-row partial; waves sharing a col-half both atomicAdd.
#pragma unroll
  for (int nt = 0; nt < 4; ++nt) {
    const int n = cbase + nt * 16 + m15;
    float p = 0.f;
#pragma unroll
    for (int mt = 0; mt < 2; ++mt)
#pragma unroll
      for (int v = 0; v < 4; ++v)
        p += acc[mt][nt][v] * wc[(rbase + mt * 16 + q * 4 + v) * N_ + n];
    p += __shfl_xor(p, 16);
    p += __shfl_xor(p, 32);
    if (q == 0) atomicAdd(&R[(size_t)bt * N_ + n], p);
  }
}

// ---------------------------------------------------------------------------
// K4: out[b,n,tau] = sum_j R[b, tau+j, n] * wt[j,n] + wb[n]
// ---------------------------------------------------------------------------
__global__ __launch_bounds__(128) void k4_conv(const float* __restrict__ R,
                                               const float* __restrict__ wt,
                                               const float* __restrict__ wb,
                                               float* __restrict__ out) {
  const int n = threadIdx.x;
  const int tau = blockIdx.x;      // 0..70
  const int b = blockIdx.y;
  float s = wb[n];
#pragma unroll
  for (int j = 0; j < NT_; ++j) {
    s += R[(b * T_ + tau + j) * N_ + n] * wt[j * N_ + n];
  }
  out[((size_t)b * N_ + n) * TOUT + tau] = s;
}

extern "C" void kernel_launch(void* const* d_in, const int* in_sizes, int n_in,
                              void* d_out, int out_size, void* d_ws, size_t ws_size,
                              hipStream_t stream) {
  (void)in_sizes; (void)n_in; (void)out_size; (void)ws_size;
  const float* x    = (const float*)d_in[0];
  // d_in[1] = targets (unused by reference)
  const float* wc   = (const float*)d_in[2];
  const float* wx   = (const float*)d_in[3];
  const float* wy   = (const float*)d_in[4];
  const float* wsx  = (const float*)d_in[5];
  const float* wsy  = (const float*)d_in[6];
  const float* wt   = (const float*)d_in[7];
  const float* wb   = (const float*)d_in[8];
  float* out = (float*)d_out;

  char* ws = (char*)d_ws;
  unsigned short* Bp = (unsigned short*)ws;   // 2304*128*2 = 589824 B
  float* R = (float*)(ws + 589824);           // 320*128*4  = 163840 B

  k1_ws<<<N_, 256, 0, stream>>>(wx, wy, wsx, wsy, Bp, R);
  dim3 g2(B_ * T_, KSPLIT);
  k2_fused<<<g2, 256, 0, stream>>>(x, Bp, wc, R);
  dim3 g4(TOUT, B_);
  k4_conv<<<g4, 128, 0, stream>>>(R, wt, wb, out);
}